// Round 12
// baseline (427.388 us; speedup 1.0000x reference)
//
#include <hip/hip_runtime.h>
#include <hip/hip_bf16.h>
#include <math.h>

// B=8, S=2048, D=512, H=8, Dh=64, u = 5*ceil(ln(2048)) = 40
#define NB 8
#define NS 2048
#define ND 512
#define NH 8
#define DHD 64
#define NU 40
#define NBH 64
#define NM 16384  // NB*NS

typedef __attribute__((ext_vector_type(8))) short short8;
typedef __attribute__((ext_vector_type(4))) short short4v;
typedef __attribute__((ext_vector_type(4))) float f32x4;

__device__ __forceinline__ short f2bf(float f) {
  __hip_bfloat16 h = __float2bfloat16(f);
  return *reinterpret_cast<short*>(&h);
}
__device__ __forceinline__ float bf2f(short s) {
  __hip_bfloat16 h;
  *reinterpret_cast<short*>(&h) = s;
  return __bfloat162float(h);
}

// async global->LDS, 16B per lane; LDS dest = wave-uniform base + lane*16
__device__ __forceinline__ void gload_lds16(const short* g, short* l) {
  __builtin_amdgcn_global_load_lds(
      (const __attribute__((address_space(1))) unsigned int*)g,
      (__attribute__((address_space(3))) unsigned int*)l, 16, 0, 0);
}

// ---------------------------------------------------------------------------
// Fused prep: blocks 0..8191 split x; 8192..8959 split+transpose W q/k/v;
// 8960..9087 fill slot8 = -1; 9088 zeroes kbarf/vbarf.
// ---------------------------------------------------------------------------
__global__ void prep(const float* __restrict__ x, const float* __restrict__ w0,
                     const float* __restrict__ w1, const float* __restrict__ w2,
                     short* __restrict__ Xs, short* __restrict__ Wts,
                     int* __restrict__ slot8, float* __restrict__ kbarf) {
  if (blockIdx.x < 8192) {
    int i = blockIdx.x * 256 + threadIdx.x;  // chunk of 4 floats
    const float4 v = *(const float4*)(x + (size_t)i * 4);
    int row = i >> 7;
    int col = (i & 127) << 2;
    float vv[4] = {v.x, v.y, v.z, v.w};
    short4v hi, lo;
#pragma unroll
    for (int j = 0; j < 4; ++j) {
      short h = f2bf(vv[j]);
      hi[j] = h;
      lo[j] = f2bf(vv[j] - bf2f(h));
    }
    *(short4v*)(Xs + (size_t)row * 1024 + col) = hi;
    *(short4v*)(Xs + (size_t)row * 1024 + 512 + col) = lo;
  } else if (blockIdx.x < 8960) {
    int bw = blockIdx.x - 8192;
    int y = bw >> 8;           // 0..2 -> wq,wk,wv
    int bxy = bw & 255;
    const float* W = y == 0 ? w0 : y == 1 ? w1 : w2;
    short* dst = Wts + (size_t)y * 512 * 1024;
    __shared__ float tile[32][33];
    int bx = bxy & 15, by = bxy >> 4;
    int k0 = bx * 32, n0 = by * 32;
    int r = threadIdx.x >> 3, cg = (threadIdx.x & 7) * 4;
    const float4 v = *(const float4*)(W + (size_t)(k0 + r) * 512 + n0 + cg);
    tile[r][cg] = v.x; tile[r][cg + 1] = v.y; tile[r][cg + 2] = v.z; tile[r][cg + 3] = v.w;
    __syncthreads();
#pragma unroll
    for (int j = 0; j < 4; ++j) {
      int kk = cg + j;
      float f = tile[kk][r];
      short h = f2bf(f);
      dst[(size_t)(n0 + r) * 1024 + k0 + kk] = h;
      dst[(size_t)(n0 + r) * 1024 + 512 + k0 + kk] = f2bf(f - bf2f(h));
    }
  } else if (blockIdx.x < 9088) {
    int base = (blockIdx.x - 8960) * 1024 + threadIdx.x * 4;  // 131072 ints
    int4 m1 = {-1, -1, -1, -1};
    *(int4*)(slot8 + base) = m1;
  } else {
    // zero kbarf+vbarf (contiguous 8192 floats)
#pragma unroll
    for (int j = 0; j < 32; ++j) kbarf[j * 256 + threadIdx.x] = 0.f;
  }
}

// ---------------------------------------------------------------------------
// Split-bf16 MFMA GEMM (QKV fused): C = X(hi+lo) @ W(hi+lo) + bias
// BM=BN=128, BK=32(real), 4 waves. Round-9 config verbatim (known 110us):
// stage-1-ahead + __syncthreads, 64KB LDS, 2 blocks/CU, grid 1536.
// Fused K/V column-mean partials in epilogue.
// ---------------------------------------------------------------------------
__global__ __launch_bounds__(256, 2) void qkvgemm(
    const short* __restrict__ A, const short* __restrict__ Wts,
    const float* __restrict__ bq, const float* __restrict__ bk,
    const float* __restrict__ bv, short* __restrict__ Qs,
    short* __restrict__ Ks, short* __restrict__ Vs,
    float* __restrict__ kbarf, float* __restrict__ vbarf) {
  __shared__ short As[2][128][64];
  __shared__ short Bs[2][128][64];
  const int bid = blockIdx.x;
  const int wgid = (bid & 7) * 192 + (bid >> 3);  // 1536 = 8*192 exact
  const int mb = wgid / 12, y = wgid % 12;
  const int m0 = mb * 128;
  const int wsel = y >> 2;
  const int n0 = (y & 3) * 128;
  const short* Wb = Wts + (size_t)wsel * 512 * 1024;
  const float* bias = wsel == 0 ? bq : wsel == 1 ? bk : bv;
  short* dstbase = wsel == 0 ? Qs : wsel == 1 ? Ks : Vs;

  const int tid = threadIdx.x;
  const int w = tid >> 6, lane = tid & 63;
  const int wm = (w >> 1) * 64, wn = (w & 1) * 64;
  const int fr = lane & 15, fk = lane >> 4;

  f32x4 acc[4][4];
  const f32x4 zz = {0.f, 0.f, 0.f, 0.f};
#pragma unroll
  for (int i = 0; i < 4; ++i)
#pragma unroll
    for (int j = 0; j < 4; ++j) acc[i][j] = zz;

  // stage one 128x32(real-k) hi+lo tile pair into buf
  auto stage = [&](int buf, int kt) {
#pragma unroll
    for (int p = 0; p < 4; ++p) {
      int idx = (p * 4 + w) * 64 + lane;   // 0..1023
      int r = idx >> 3, c = idx & 7;
      int cs = c ^ (r & 7);                // inverse-swizzled source chunk
      int sc = (cs < 4) ? (kt + cs * 8) : (512 + kt + (cs - 4) * 8);
      short* lA = &As[buf][0][0] + (p * 4 + w) * 512;
      short* lB = &Bs[buf][0][0] + (p * 4 + w) * 512;
      gload_lds16(A + (size_t)(m0 + r) * 1024 + sc, lA);
      gload_lds16(Wb + (size_t)(n0 + r) * 1024 + sc, lB);
    }
  };

  stage(0, 0);
  __syncthreads();
  for (int kt = 0; kt < 512; kt += 32) {
    int cur = (kt >> 5) & 1;
    if (kt + 32 < 512) stage(cur ^ 1, kt + 32);
    short8 ah[4], al[4], bh[4], bl[4];
#pragma unroll
    for (int mf = 0; mf < 4; ++mf) {
      int r = wm + mf * 16 + fr;
      ah[mf] = *(const short8*)&As[cur][r][(fk ^ (r & 7)) << 3];
      al[mf] = *(const short8*)&As[cur][r][((4 + fk) ^ (r & 7)) << 3];
    }
#pragma unroll
    for (int nf = 0; nf < 4; ++nf) {
      int r = wn + nf * 16 + fr;
      bh[nf] = *(const short8*)&Bs[cur][r][(fk ^ (r & 7)) << 3];
      bl[nf] = *(const short8*)&Bs[cur][r][((4 + fk) ^ (r & 7)) << 3];
    }
#pragma unroll
    for (int mf = 0; mf < 4; ++mf)
#pragma unroll
      for (int nf = 0; nf < 4; ++nf) {
        // swapped operands: D[n][m]; terms Whi*Xhi + Whi*Xlo + Wlo*Xhi
        acc[mf][nf] = __builtin_amdgcn_mfma_f32_16x16x32_bf16(bh[nf], ah[mf], acc[mf][nf], 0, 0, 0);
        acc[mf][nf] = __builtin_amdgcn_mfma_f32_16x16x32_bf16(bh[nf], al[mf], acc[mf][nf], 0, 0, 0);
        acc[mf][nf] = __builtin_amdgcn_mfma_f32_16x16x32_bf16(bl[nf], ah[mf], acc[mf][nf], 0, 0, 0);
      }
    __syncthreads();
  }

  // epilogue: lane holds (m = m0+wm+mf*16+fr) x (n = n0+wn+nf*16+fk*4+j)
  float csum[4][4];
#pragma unroll
  for (int nf = 0; nf < 4; ++nf)
#pragma unroll
    for (int j = 0; j < 4; ++j) csum[nf][j] = 0.f;

#pragma unroll
  for (int mf = 0; mf < 4; ++mf) {
    int m = m0 + wm + mf * 16 + fr;
    int b = m >> 11, s = m & 2047;
#pragma unroll
    for (int nf = 0; nf < 4; ++nf) {
      int nb = n0 + wn + nf * 16 + fk * 4;
      float4 bi4 = *(const float4*)(bias + nb);
      int h = nb >> 6, dh = nb & 63;
      short* dst = dstbase + ((size_t)((b << 3) + h) * 2048 + s) * 128;
      short4v hi, lo;
      float bb[4] = {bi4.x, bi4.y, bi4.z, bi4.w};
#pragma unroll
      for (int j = 0; j < 4; ++j) {
        float v = acc[mf][nf][j] + bb[j];
        csum[nf][j] += v;
        short hs = f2bf(v);
        hi[j] = hs;
        lo[j] = f2bf(v - bf2f(hs));
      }
      *(short4v*)(dst + dh) = hi;
      *(short4v*)(dst + 64 + dh) = lo;
    }
  }

  // fused K/V column-mean partials (whole block lies in one batch)
  if (wsel != 0) {
    float* bar = (wsel == 1) ? kbarf : vbarf;
    int b = m0 >> 11;
#pragma unroll
    for (int nf = 0; nf < 4; ++nf)
#pragma unroll
      for (int j = 0; j < 4; ++j) {
        float s = csum[nf][j];
        s += __shfl_xor(s, 1, 64);
        s += __shfl_xor(s, 2, 64);
        s += __shfl_xor(s, 4, 64);
        s += __shfl_xor(s, 8, 64);
        if (fr == 0) {
          int cfull = n0 + wn + nf * 16 + fk * 4 + j;
          int h = cfull >> 6, dh = cfull & 63;
          atomicAdd(bar + ((b << 3) + h) * 64 + dh, s * (1.f / 2048.f));
        }
      }
  }
}

// ---------------------------------------------------------------------------
// QK^T row-max, KEY-PARTITIONED waves, BARRIER-FREE, REG-DOUBLE-BUFFERED:
// block owns 128 q-rows in regs; wave w streams its 32-key slices from L2
// with a 2-deep register pipeline (load t+1 before MFMAs on t).
// Grid 1024 = 64 bh x 16 q-blocks, XCD-swizzled. Fused M=(max-q.kbar)/8.
// ---------------------------------------------------------------------------
__global__ __launch_bounds__(256, 2) void qkmax(const short* __restrict__ Qs,
                                                const short* __restrict__ Ks,
                                                const float* __restrict__ kbarf,
                                                float* __restrict__ Mval) {
  __shared__ float red[4][128];
  const int bid = blockIdx.x;
  const int wgid = (bid & 7) * 128 + (bid >> 3);  // 1024 = 8*128 exact
  const int bh = wgid >> 4, q0 = (wgid & 15) * 128;
  const short* Qb = Qs + ((size_t)bh * 2048 + q0) * 128;
  const short* Kb = Ks + (size_t)bh * 2048 * 128;
  const int tid = threadIdx.x, w = tid >> 6, lane = tid & 63;
  const int fr = lane & 15, fk = lane >> 4;

  // ALL 128 q-rows as A-fragments in registers (tile-invariant)
  short8 qf[8][2][2];
#pragma unroll
  for (int mf = 0; mf < 8; ++mf) {
    int row = mf * 16 + fr;
#pragma unroll
    for (int hl = 0; hl < 2; ++hl)
#pragma unroll
      for (int k0 = 0; k0 < 2; ++k0)
        qf[mf][hl][k0] =
            *(const short8*)(Qb + (size_t)row * 128 + hl * 64 + k0 * 32 + fk * 8);
  }

  f32x4 rmax[8];
#pragma unroll
  for (int mf = 0; mf < 8; ++mf)
#pragma unroll
    for (int j = 0; j < 4; ++j) rmax[mf][j] = -1e30f;
  const f32x4 zz = {0.f, 0.f, 0.f, 0.f};

  // one K fragment set: [nf*4 + hilo*2 + k0], 8 x short8 = 32 VGPR
  short8 seta[8], setb[8];
  auto loadK = [&](short8* dst, int t) {
    const short* Kt = Kb + (size_t)t * 128 * 128;
#pragma unroll
    for (int nf = 0; nf < 2; ++nf) {
      const short* kr = Kt + (size_t)(w * 32 + nf * 16 + fr) * 128 + fk * 8;
#pragma unroll
      for (int k0 = 0; k0 < 2; ++k0) {
        dst[nf * 4 + k0] = *(const short8*)(kr + k0 * 32);            // hi
        dst[nf * 4 + 2 + k0] = *(const short8*)(kr + 64 + k0 * 32);   // lo
      }
    }
  };
  auto mfmaK = [&](const short8* s) {
#pragma unroll
    for (int nf = 0; nf < 2; ++nf)
#pragma unroll
      for (int mf = 0; mf < 8; ++mf) {
        f32x4 a = zz;
#pragma unroll
        for (int k0 = 0; k0 < 2; ++k0) {
          a = __builtin_amdgcn_mfma_f32_16x16x32_bf16(qf[mf][0][k0], s[nf * 4 + k0], a, 0, 0, 0);
          a = __builtin_amdgcn_mfma_f32_16x16x32_bf16(qf[mf][0][k0], s[nf * 4 + 2 + k0], a, 0, 0, 0);
          a = __builtin_amdgcn_mfma_f32_16x16x32_bf16(qf[mf][1][k0], s[nf * 4 + k0], a, 0, 0, 0);
        }
#pragma unroll
        for (int j = 0; j < 4; ++j) rmax[mf][j] = fmaxf(rmax[mf][j], a[j]);
      }
  };

  loadK(seta, 0);
#pragma unroll 1
  for (int t = 0; t < 16; t += 2) {
    loadK(setb, t + 1);
    mfmaK(seta);
    if (t + 2 < 16) loadK(seta, t + 2);
    mfmaK(setb);
  }

  // intra-wave reduce over 16 key lanes; lane fr==0 holds q = mf*16+fk*4+j
#pragma unroll
  for (int mf = 0; mf < 8; ++mf)
#pragma unroll
    for (int j = 0; j < 4; ++j) {
      float r = rmax[mf][j];
      r = fmaxf(r, __shfl_xor(r, 1, 64));
      r = fmaxf(r, __shfl_xor(r, 2, 64));
      r = fmaxf(r, __shfl_xor(r, 4, 64));
      r = fmaxf(r, __shfl_xor(r, 8, 64));
      if (fr == 0) red[w][mf * 16 + fk * 4 + j] = r;
    }
  __syncthreads();

  // cross-wave combine + fused M = (max - q.kbar)/8, one thread per q-row
  if (tid < 128) {
    float mx = fmaxf(fmaxf(red[0][tid], red[1][tid]),
                     fmaxf(red[2][tid], red[3][tid]));
    const short* qp = Qb + (size_t)tid * 128;
    const float* kb = kbarf + bh * 64;
    float dot = 0.f;
#pragma unroll
    for (int ch = 0; ch < 8; ++ch) {
      short8 hi = *(const short8*)(qp + ch * 8);
      short8 lo = *(const short8*)(qp + 64 + ch * 8);
#pragma unroll
      for (int e = 0; e < 8; ++e) dot += (bf2f(hi[e]) + bf2f(lo[e])) * kb[ch * 8 + e];
    }
    Mval[(size_t)bh * 2048 + q0 + tid] = (mx - dot) * 0.125f;
  }
}

// ---------------------------------------------------------------------------
// top-40 per (bh): one WAVE per bh; also writes slot map for the output pass.
// ---------------------------------------------------------------------------
__global__ __launch_bounds__(256) void topk40(const float* __restrict__ Mval,
                                              int* __restrict__ tidx,
                                              int* __restrict__ slot8) {
  __shared__ float vals[4][32][64];
  const int w = threadIdx.x >> 6, lane = threadIdx.x & 63;
  const int bh = blockIdx.x * 4 + w;
  const float* src = Mval + (size_t)bh * 2048;
#pragma unroll
  for (int j = 0; j < 32; ++j) vals[w][j][lane] = src[j * 64 + lane];

  for (int it = 0; it < NU; ++it) {
    float best = -INFINITY;
    int bi = 1 << 30;
#pragma unroll
    for (int j = 0; j < 32; ++j) {
      float x = vals[w][j][lane];
      int idx = j * 64 + lane;
      if (x > best) { best = x; bi = idx; }
    }
#pragma unroll
    for (int off = 1; off < 64; off <<= 1) {
      float ov = __shfl_xor(best, off, 64);
      int oi = __shfl_xor(bi, off, 64);
      if (ov > best || (ov == best && oi < bi)) { best = ov; bi = oi; }
    }
    if (lane == 0) {
      tidx[bh * NU + it] = bi;
      slot8[((size_t)(bh >> 3) * 2048 + bi) * 8 + (bh & 7)] = it;
    }
    if ((bi & 63) == lane) vals[w][bi >> 6][lane] = -INFINITY;
  }
}

// ---------------------------------------------------------------------------
// Dense attention for 40 selected queries, key-split over 4 chunks (partials)
// ---------------------------------------------------------------------------
__global__ __launch_bounds__(256) void topattn1(const short* __restrict__ Qs,
                                                const short* __restrict__ Ks,
                                                const short* __restrict__ Vs,
                                                const int* __restrict__ topidx,
                                                float* __restrict__ pacc,
                                                float* __restrict__ pm,
                                                float* __restrict__ pl) {
  __shared__ float qs[40][68];
  __shared__ float Kst[64][132];
  __shared__ float Vsh[128][68];
  __shared__ float st[40][132];
  __shared__ float m_s[40], l_s[40], r_s[40];
  __shared__ int tix[40];
  const int tid = threadIdx.x;
  const int bh = blockIdx.x, kc = blockIdx.y;
  const short* Kb = Ks + (size_t)bh * 2048 * 128;
  const short* Vb = Vs + (size_t)bh * 2048 * 128;

  if (tid < 40) {
    tix[tid] = topidx[bh * NU + tid];
    m_s[tid] = -INFINITY;
    l_s[tid] = 0.f;
  }
  __syncthreads();
  for (int i = tid; i < 40 * 64; i += 256) {
    int q = i >> 6, dd2 = i & 63;
    const short* qp = Qs + ((size_t)bh * 2048 + tix[q]) * 128;
    qs[q][dd2] = bf2f(qp[dd2]) + bf2f(qp[64 + dd2]);
  }
  const int tx = tid & 31, ty = tid >> 5;
  const int d = tid & 63, qb = tid >> 6;
  float acc[10];
#pragma unroll
  for (int j = 0; j < 10; ++j) acc[j] = 0.f;
  __syncthreads();

  for (int t = 0; t < 4; ++t) {
    int krow0 = kc * 512 + t * 128;
#pragma unroll
    for (int p = 0; p < 4; ++p) {
      int idx = tid + (p << 8);
      int r = idx >> 3, cg = (idx & 7) << 3;
      const short8 kh = *(const short8*)(Kb + (size_t)(krow0 + r) * 128 + cg);
      const short8 kl = *(const short8*)(Kb + (size_t)(krow0 + r) * 128 + 64 + cg);
      const short8 vh = *(const short8*)(Vb + (size_t)(krow0 + r) * 128 + cg);
      const short8 vl = *(const short8*)(Vb + (size_t)(krow0 + r) * 128 + 64 + cg);
#pragma unroll
      for (int j = 0; j < 8; ++j) {
        Kst[cg + j][r] = bf2f(kh[j]) + bf2f(kl[j]);
        Vsh[r][cg + j] = bf2f(vh[j]) + bf2f(vl[j]);
      }
    }
    __syncthreads();

    {
      float c5[5][4];
#pragma unroll
      for (int i = 0; i < 5; ++i)
#pragma unroll
        for (int j = 0; j < 4; ++j) c5[i][j] = 0.f;
      for (int dd = 0; dd < 64; ++dd) {
        const float4 b4 = *(const float4*)&Kst[dd][tx << 2];
#pragma unroll
        for (int i = 0; i < 5; ++i) {
          float a = qs[ty * 5 + i][dd];
          c5[i][0] = fmaf(a, b4.x, c5[i][0]);
          c5[i][1] = fmaf(a, b4.y, c5[i][1]);
          c5[i][2] = fmaf(a, b4.z, c5[i][2]);
          c5[i][3] = fmaf(a, b4.w, c5[i][3]);
        }
      }
#pragma unroll
      for (int i = 0; i < 5; ++i) {
        float4 o;
        o.x = c5[i][0] * 0.125f; o.y = c5[i][1] * 0.125f;
        o.z = c5[i][2] * 0.125f; o.w = c5[i][3] * 0.125f;
        *(float4*)&st[ty * 5 + i][tx << 2] = o;
      }
    }
    __syncthreads();

    if (tid < 160) {
      int q = tid >> 2, sub = tid & 3;
      float tm = -INFINITY;
#pragma unroll
      for (int kk = 0; kk < 32; ++kk) tm = fmaxf(tm, st[q][sub * 32 + kk]);
      tm = fmaxf(tm, __shfl_xor(tm, 1, 64));
      tm = fmaxf(tm, __shfl_xor(tm, 2, 64));
      float mold = m_s[q];
      float mnew = fmaxf(mold, tm);
      float sum = 0.f;
#pragma unroll
      for (int kk = 0; kk < 32; ++kk) {
        float ww = __expf(st[q][sub * 32 + kk] - mnew);
        st[q][sub * 32 + kk] = ww;
        sum += ww;
      }
      sum += __shfl_xor(sum, 1, 64);
      sum += __shfl_xor(sum, 2, 64);
      if (sub == 0) {
        float r = __expf(mold - mnew);
        l_s[q] = l_s[q] * r + sum;
        m_s[q] = mnew;
        r_s[q] = r;
      }
    }
    __syncthreads();

#pragma unroll
    for (int j = 0; j < 10; ++j) {
      int q = qb + (j << 2);
      float a = 0.f;
#pragma unroll
      for (int kk = 0; kk < 128; kk += 4) {
        float4 ww = *(const float4*)&st[q][kk];
        a = fmaf(ww.x, Vsh[kk + 0][d], a);
        a = fmaf(ww.y, Vsh[kk + 1][d], a);
        a = fmaf(ww.z, Vsh[kk + 2][d], a);
        a = fmaf(ww.w, Vsh[kk + 3][d], a);
      }
      acc[j] = acc[j] * r_s[q] + a;
    }
    __syncthreads();
  }

  int pcb = bh * 4 + kc;
#pragma unroll
  for (int j = 0; j < 10; ++j) {
    int q = qb + (j << 2);
    pacc[((size_t)pcb * NU + q) * 64 + d] = acc[j];
  }
  if (tid < 40) {
    pm[pcb * NU + tid] = m_s[tid];
    pl[pcb * NU + tid] = l_s[tid];
  }
}

// ---------------------------------------------------------------------------
// Blocks 0..63: combine partials -> tout; blocks 64..127: om = vbar@Wo+bo
// ---------------------------------------------------------------------------
__global__ __launch_bounds__(256) void topcombine(const float* __restrict__ pacc,
                                                  const float* __restrict__ pm,
                                                  const float* __restrict__ pl,
                                                  float* __restrict__ tout,
                                                  const float* __restrict__ vbarf,
                                                  const float* __restrict__ Wo,
                                                  const float* __restrict__ bo,
                                                  float* __restrict__ om) {
  if (blockIdx.x < 64) {
    const int bh = blockIdx.x;
    const int d = threadIdx.x & 63, qb = threadIdx.x >> 6;
#pragma unroll
    for (int j = 0; j < 10; ++j) {
      int q = qb + (j << 2);
      float m0 = pm[(bh * 4 + 0) * NU + q], m1 = pm[(bh * 4 + 1) * NU + q];
      float m2 = pm[(bh * 4 + 2) * NU + q], m3 = pm[(bh * 4 + 3) * NU + q];
      float mx = fmaxf(fmaxf(m0, m1), fmaxf(m2, m3));
      float e0 = __expf(m0 - mx), e1 = __expf(m1 - mx);
      float e2 = __expf(m2 - mx), e3 = __expf(m3 - mx);
      float L = pl[(bh * 4 + 0) * NU + q] * e0 + pl[(bh * 4 + 1) * NU + q] * e1 +
                pl[(bh * 4 + 2) * NU + q] * e2 + pl[(bh * 4 + 3) * NU + q] * e3;
      float o = (pacc[((size_t)(bh * 4 + 0) * NU + q) * 64 + d] * e0 +
                 pacc[((size_t)(bh * 4 + 1) * NU + q) * 64 + d] * e1 +
                 pacc[((size_t)(bh * 4 + 2) * NU + q) * 64 + d] * e2 +
                 pacc[((size_t)(bh * 4 + 3) * NU + q) * 64 + d] * e3) / L;
      tout[((size_t)bh * NU + q) * 64 + d] = o;
    }
  } else {
    __shared__ float mred[4][64];
    int blk2 = blockIdx.x - 64;          // 0..63
    int b = blk2 >> 3, n0 = (blk2 & 7) * 64;
    int n = n0 + (threadIdx.x & 63), kq = threadIdx.x >> 6;
    const float* vb = vbarf + b * 512;
    float acc = 0.f;
#pragma unroll 8
    for (int k = kq * 128; k < kq * 128 + 128; ++k)
      acc = fmaf(vb[k], Wo[(size_t)k * 512 + n], acc);
    mred[kq][threadIdx.x & 63] = acc;
    __syncthreads();
    if (kq == 0)
      om[b * 512 + n] = bo[n] + mred[0][n - n0] + mred[1][n - n0] +
                        mred[2][n - n0] + mred[3][n - n0];
  }
}

// ---------------------------------------------------------------------------
// Fused output: out[r] = om[b] + sum over selected heads of (tout-vbar)@Wo_h.
// ---------------------------------------------------------------------------
__global__ __launch_bounds__(256) void outall(const float* __restrict__ om,
                                              const int* __restrict__ slot8,
                                              const float* __restrict__ tout,
                                              const float* __restrict__ vbarf,
                                              const float* __restrict__ Wo,
                                              float* __restrict__ out) {
  const int r = blockIdx.x;
  const int b = r >> 11;
  const int n = threadIdx.x;
  float o0 = om[b * 512 + n];
  float o1 = om[b * 512 + n + 256];
  __shared__ float dsh[64];
#pragma unroll
  for (int h = 0; h < 8; ++h) {
    int it = slot8[(size_t)r * 8 + h];
    if (it >= 0) {
      int bh = b * 8 + h;
      int g = bh * NU + it;
      __syncthreads();
      if (n < 64) dsh[n] = tout[(size_t)g * 64 + n] - vbarf[bh * 64 + n];
      __syncthreads();
#pragma unroll 8
      for (int dh = 0; dh < 64; ++dh) {
        float d = dsh[dh];
        const float* wrow = Wo + (size_t)(h * 64 + dh) * 512;
        o0 = fmaf(d, wrow[n], o0);
        o1 = fmaf(d, wrow[n + 256], o1);
      }
    }
  }
  out[(size_t)r * 512 + n] = o0;
  out[(size_t)r * 512 + n + 256] = o1;
}

// ---------------------------------------------------------------------------
extern "C" void kernel_launch(void* const* d_in, const int* in_sizes, int n_in,
                              void* d_out, int out_size, void* d_ws, size_t ws_size,
                              hipStream_t stream) {
  (void)in_sizes; (void)n_in; (void)out_size; (void)ws_size;
  const float* x  = (const float*)d_in[0];
  const float* wq = (const float*)d_in[1];
  const float* bq = (const float*)d_in[2];
  const float* wk = (const float*)d_in[3];
  const float* bk = (const float*)d_in[4];
  const float* wv = (const float*)d_in[5];
  const float* bv = (const float*)d_in[6];
  const float* wo = (const float*)d_in[7];
  const float* bo = (const float*)d_in[8];
  float* out = (float*)d_out;

  short* Xs   = (short*)d_ws;                              // 16384*1024
  short* Wts  = Xs + (size_t)16384 * 1024;                 // 3*512*1024
  short* Qsb  = Wts + (size_t)3 * 512 * 1024;              // 64*2048*128 each
  short* Ksb  = Qsb + (size_t)NBH * NS * 128;
  short* Vsb  = Ksb + (size_t)NBH * NS * 128;
  float* Mval = (float*)(Vsb + (size_t)NBH * NS * 128);    // 131072
  float* kbarf = Mval + (size_t)NBH * NS;                  // 4096
  float* vbarf = kbarf + NBH * 64;                         // 4096 (contig after kbarf)
  int* tidx   = (int*)(vbarf + NBH * 64);                  // 2560
  int* slot8  = tidx + NBH * NU;                           // 131072
  float* pacc = (float*)(slot8 + (size_t)NM * 8);          // 64*4*40*64
  float* pm   = pacc + (size_t)NBH * 4 * NU * 64;          // 10240
  float* pl   = pm + NBH * 4 * NU;                         // 10240
  float* tout = pl + NBH * 4 * NU;                         // 64*40*64
  float* om   = tout + (size_t)NBH * NU * 64;              // 4096

  prep<<<9089, 256, 0, stream>>>(x, wq, wk, wv, Xs, Wts, slot8, kbarf);
  qkvgemm<<<1536, 256, 0, stream>>>(Xs, Wts, bq, bk, bv, Qsb, Ksb, Vsb, kbarf, vbarf);
  qkmax<<<1024, 256, 0, stream>>>(Qsb, Ksb, kbarf, Mval);
  topk40<<<16, 256, 0, stream>>>(Mval, tidx, slot8);
  topattn1<<<dim3(NBH, 4), 256, 0, stream>>>(Qsb, Ksb, Vsb, tidx, pacc, pm, pl);
  topcombine<<<128, 256, 0, stream>>>(pacc, pm, pl, tout, vbarf, wo, bo, om);
  outall<<<NM, 256, 0, stream>>>(om, slot8, tout, vbarf, wo, out);
}

// Round 13
// 336.932 us; speedup vs baseline: 1.2685x; 1.2685x over previous
//
#include <hip/hip_runtime.h>
#include <hip/hip_bf16.h>
#include <math.h>

// B=8, S=2048, D=512, H=8, Dh=64, u = 5*ceil(ln(2048)) = 40
#define NB 8
#define NS 2048
#define ND 512
#define NH 8
#define DHD 64
#define NU 40
#define NBH 64
#define NM 16384  // NB*NS

typedef __attribute__((ext_vector_type(8))) short short8;
typedef __attribute__((ext_vector_type(4))) short short4v;
typedef __attribute__((ext_vector_type(4))) float f32x4;

__device__ __forceinline__ short f2bf(float f) {
  __hip_bfloat16 h = __float2bfloat16(f);
  return *reinterpret_cast<short*>(&h);
}
__device__ __forceinline__ float bf2f(short s) {
  __hip_bfloat16 h;
  *reinterpret_cast<short*>(&h) = s;
  return __bfloat162float(h);
}

// async global->LDS, 16B per lane; LDS dest = wave-uniform base + lane*16
__device__ __forceinline__ void gload_lds16(const void* g, void* l) {
  __builtin_amdgcn_global_load_lds(
      (const __attribute__((address_space(1))) unsigned int*)g,
      (__attribute__((address_space(3))) unsigned int*)l, 16, 0, 0);
}

// ---------------------------------------------------------------------------
// prep: blocks 0..767 split+transpose W q/k/v; 768..895 fill slot8 = -1;
// 896 zeroes kbarf/vbarf.  (x is no longer pre-split: qkvgemm stages fp32.)
// ---------------------------------------------------------------------------
__global__ void prep(const float* __restrict__ w0,
                     const float* __restrict__ w1, const float* __restrict__ w2,
                     short* __restrict__ Wts,
                     int* __restrict__ slot8, float* __restrict__ kbarf) {
  if (blockIdx.x < 768) {
    int bw = blockIdx.x;
    int y = bw >> 8;           // 0..2 -> wq,wk,wv
    int bxy = bw & 255;
    const float* W = y == 0 ? w0 : y == 1 ? w1 : w2;
    short* dst = Wts + (size_t)y * 512 * 1024;
    __shared__ float tile[32][33];
    int bx = bxy & 15, by = bxy >> 4;
    int k0 = bx * 32, n0 = by * 32;
    int r = threadIdx.x >> 3, cg = (threadIdx.x & 7) * 4;
    const float4 v = *(const float4*)(W + (size_t)(k0 + r) * 512 + n0 + cg);
    tile[r][cg] = v.x; tile[r][cg + 1] = v.y; tile[r][cg + 2] = v.z; tile[r][cg + 3] = v.w;
    __syncthreads();
#pragma unroll
    for (int j = 0; j < 4; ++j) {
      int kk = cg + j;
      float f = tile[kk][r];
      short h = f2bf(f);
      dst[(size_t)(n0 + r) * 1024 + k0 + kk] = h;
      dst[(size_t)(n0 + r) * 1024 + 512 + k0 + kk] = f2bf(f - bf2f(h));
    }
  } else if (blockIdx.x < 896) {
    int base = (blockIdx.x - 768) * 1024 + threadIdx.x * 4;  // 131072 ints
    int4 m1 = {-1, -1, -1, -1};
    *(int4*)(slot8 + base) = m1;
  } else {
    // zero kbarf+vbarf (contiguous 8192 floats)
#pragma unroll
    for (int j = 0; j < 32; ++j) kbarf[j * 256 + threadIdx.x] = 0.f;
  }
}

// ---------------------------------------------------------------------------
// Split-bf16 MFMA GEMM (QKV fused): C = X(hi+lo) @ W(hi+lo) + bias
// BM=BN=128, BK=32, 4 waves. Round-9 schedule (stage-1-ahead + __syncthreads).
// A staged as FP32 directly from x (same bytes as hi+lo bf16); hi/lo
// decomposition done in-register after ds_read. Fused K/V col-mean partials.
// ---------------------------------------------------------------------------
__global__ __launch_bounds__(256, 2) void qkvgemm(
    const float* __restrict__ X, const short* __restrict__ Wts,
    const float* __restrict__ bq, const float* __restrict__ bk,
    const float* __restrict__ bv, short* __restrict__ Qs,
    short* __restrict__ Ks, short* __restrict__ Vs,
    float* __restrict__ kbarf, float* __restrict__ vbarf) {
  __shared__ float Asf[2][128][32];   // fp32 A tile, 16B chunks XOR-swizzled
  __shared__ short Bs[2][128][64];
  const int bid = blockIdx.x;
  const int wgid = (bid & 7) * 192 + (bid >> 3);  // 1536 = 8*192 exact
  const int mb = wgid / 12, y = wgid % 12;
  const int m0 = mb * 128;
  const int wsel = y >> 2;
  const int n0 = (y & 3) * 128;
  const short* Wb = Wts + (size_t)wsel * 512 * 1024;
  const float* bias = wsel == 0 ? bq : wsel == 1 ? bk : bv;
  short* dstbase = wsel == 0 ? Qs : wsel == 1 ? Ks : Vs;

  const int tid = threadIdx.x;
  const int w = tid >> 6, lane = tid & 63;
  const int wm = (w >> 1) * 64, wn = (w & 1) * 64;
  const int fr = lane & 15, fk = lane >> 4;

  f32x4 acc[4][4];
  const f32x4 zz = {0.f, 0.f, 0.f, 0.f};
#pragma unroll
  for (int i = 0; i < 4; ++i)
#pragma unroll
    for (int j = 0; j < 4; ++j) acc[i][j] = zz;

  // stage one tile pair into buf: A fp32 (16KB) + B split-bf16 (16KB)
  auto stage = [&](int buf, int kt) {
#pragma unroll
    for (int p = 0; p < 4; ++p) {
      int idx = (p * 4 + w) * 64 + lane;   // 0..1023
      int r = idx >> 3, c = idx & 7;
      int cs = c ^ (r & 7);                // inverse-swizzled source chunk
      // A: fp32 row chunk (4 floats)
      float* lA = &Asf[buf][0][0] + (p * 4 + w) * 256;
      gload_lds16(X + (size_t)(m0 + r) * 512 + kt + cs * 4, lA);
      // B: split-bf16 row chunk (8 shorts)
      int sc = (cs < 4) ? (kt + cs * 8) : (512 + kt + (cs - 4) * 8);
      short* lB = &Bs[buf][0][0] + (p * 4 + w) * 512;
      gload_lds16(Wb + (size_t)(n0 + r) * 1024 + sc, lB);
    }
  };

  stage(0, 0);
  __syncthreads();
  for (int kt = 0; kt < 512; kt += 32) {
    int cur = (kt >> 5) & 1;
    if (kt + 32 < 512) stage(cur ^ 1, kt + 32);
    short8 ah[4], al[4], bh[4], bl[4];
#pragma unroll
    for (int mf = 0; mf < 4; ++mf) {
      int r = wm + mf * 16 + fr;
      const float4 f0 = *(const float4*)&Asf[cur][r][((2 * fk) ^ (r & 7)) << 2];
      const float4 f1 = *(const float4*)&Asf[cur][r][((2 * fk + 1) ^ (r & 7)) << 2];
      float fv[8] = {f0.x, f0.y, f0.z, f0.w, f1.x, f1.y, f1.z, f1.w};
      short8 hi8, lo8;
#pragma unroll
      for (int e = 0; e < 8; ++e) {
        short hs = f2bf(fv[e]);
        hi8[e] = hs;
        lo8[e] = f2bf(fv[e] - bf2f(hs));
      }
      ah[mf] = hi8;
      al[mf] = lo8;
    }
#pragma unroll
    for (int nf = 0; nf < 4; ++nf) {
      int r = wn + nf * 16 + fr;
      bh[nf] = *(const short8*)&Bs[cur][r][(fk ^ (r & 7)) << 3];
      bl[nf] = *(const short8*)&Bs[cur][r][((4 + fk) ^ (r & 7)) << 3];
    }
#pragma unroll
    for (int mf = 0; mf < 4; ++mf)
#pragma unroll
      for (int nf = 0; nf < 4; ++nf) {
        // swapped operands: D[n][m]; terms Whi*Xhi + Whi*Xlo + Wlo*Xhi
        acc[mf][nf] = __builtin_amdgcn_mfma_f32_16x16x32_bf16(bh[nf], ah[mf], acc[mf][nf], 0, 0, 0);
        acc[mf][nf] = __builtin_amdgcn_mfma_f32_16x16x32_bf16(bh[nf], al[mf], acc[mf][nf], 0, 0, 0);
        acc[mf][nf] = __builtin_amdgcn_mfma_f32_16x16x32_bf16(bl[nf], ah[mf], acc[mf][nf], 0, 0, 0);
      }
    __syncthreads();
  }

  // epilogue: lane holds (m = m0+wm+mf*16+fr) x (n = n0+wn+nf*16+fk*4+j)
  float csum[4][4];
#pragma unroll
  for (int nf = 0; nf < 4; ++nf)
#pragma unroll
    for (int j = 0; j < 4; ++j) csum[nf][j] = 0.f;

#pragma unroll
  for (int mf = 0; mf < 4; ++mf) {
    int m = m0 + wm + mf * 16 + fr;
    int b = m >> 11, s = m & 2047;
#pragma unroll
    for (int nf = 0; nf < 4; ++nf) {
      int nb = n0 + wn + nf * 16 + fk * 4;
      float4 bi4 = *(const float4*)(bias + nb);
      int h = nb >> 6, dh = nb & 63;
      short* dst = dstbase + ((size_t)((b << 3) + h) * 2048 + s) * 128;
      short4v hi, lo;
      float bb[4] = {bi4.x, bi4.y, bi4.z, bi4.w};
#pragma unroll
      for (int j = 0; j < 4; ++j) {
        float v = acc[mf][nf][j] + bb[j];
        csum[nf][j] += v;
        short hs = f2bf(v);
        hi[j] = hs;
        lo[j] = f2bf(v - bf2f(hs));
      }
      *(short4v*)(dst + dh) = hi;
      *(short4v*)(dst + 64 + dh) = lo;
    }
  }

  // fused K/V column-mean partials (whole block lies in one batch)
  if (wsel != 0) {
    float* bar = (wsel == 1) ? kbarf : vbarf;
    int b = m0 >> 11;
#pragma unroll
    for (int nf = 0; nf < 4; ++nf)
#pragma unroll
      for (int j = 0; j < 4; ++j) {
        float s = csum[nf][j];
        s += __shfl_xor(s, 1, 64);
        s += __shfl_xor(s, 2, 64);
        s += __shfl_xor(s, 4, 64);
        s += __shfl_xor(s, 8, 64);
        if (fr == 0) {
          int cfull = n0 + wn + nf * 16 + fk * 4 + j;
          int h = cfull >> 6, dh = cfull & 63;
          atomicAdd(bar + ((b << 3) + h) * 64 + dh, s * (1.f / 2048.f));
        }
      }
  }
}

// ---------------------------------------------------------------------------
// QK^T row-max, KEY-PARTITIONED waves (round-9 schedule: LDS dbuf,
// stage-1-ahead + __syncthreads). Block owns 128 q-rows in regs; wave w owns
// 32 keys/tile. Grid 1024 = 64 bh x 16 q-blocks, XCD-swizzled.
// Fused M=(max-q.kbar)/8.
// ---------------------------------------------------------------------------
__global__ __launch_bounds__(256, 2) void qkmax(const short* __restrict__ Qs,
                                                const short* __restrict__ Ks,
                                                const float* __restrict__ kbarf,
                                                float* __restrict__ Mval) {
  __shared__ short Kt[2][128][128];
  __shared__ float red[4][128];
  const int bid = blockIdx.x;
  const int wgid = (bid & 7) * 128 + (bid >> 3);  // 1024 = 8*128 exact
  const int bh = wgid >> 4, q0 = (wgid & 15) * 128;
  const short* Qb = Qs + ((size_t)bh * 2048 + q0) * 128;
  const short* Kb = Ks + (size_t)bh * 2048 * 128;
  const int tid = threadIdx.x, w = tid >> 6, lane = tid & 63;
  const int fr = lane & 15, fk = lane >> 4;

  // ALL 128 q-rows as A-fragments in registers (tile-invariant)
  short8 qf[8][2][2];
#pragma unroll
  for (int mf = 0; mf < 8; ++mf) {
    int row = mf * 16 + fr;
#pragma unroll
    for (int hl = 0; hl < 2; ++hl)
#pragma unroll
      for (int k0 = 0; k0 < 2; ++k0)
        qf[mf][hl][k0] =
            *(const short8*)(Qb + (size_t)row * 128 + hl * 64 + k0 * 32 + fk * 8);
  }

  f32x4 rmax[8];
#pragma unroll
  for (int mf = 0; mf < 8; ++mf)
#pragma unroll
    for (int j = 0; j < 4; ++j) rmax[mf][j] = -1e30f;
  const f32x4 zz = {0.f, 0.f, 0.f, 0.f};

  auto stageK = [&](int buf, int t) {
#pragma unroll
    for (int p = 0; p < 8; ++p) {
      int idx = p * 256 + tid;            // 0..2047
      int r = idx >> 4, c = idx & 15;
      int cs = c ^ (r & 15);
      short* lb = &Kt[buf][0][0] + (size_t)(p * 256 + w * 64) * 8;
      gload_lds16(Kb + (size_t)(t * 128 + r) * 128 + cs * 8, lb);
    }
  };

  stageK(0, 0);
  __syncthreads();
  for (int t = 0; t < 16; ++t) {
    const int cur = t & 1;
    if (t < 15) stageK(cur ^ 1, t + 1);
#pragma unroll
    for (int nf = 0; nf < 2; ++nf) {
      int r = w * 32 + nf * 16 + fr;      // this wave's key rows
      short8 kfh[2], kfl[2];
#pragma unroll
      for (int k0 = 0; k0 < 2; ++k0) {
        kfh[k0] = *(const short8*)&Kt[cur][r][((k0 * 4 + fk) ^ (r & 15)) << 3];
        kfl[k0] = *(const short8*)&Kt[cur][r][((8 + k0 * 4 + fk) ^ (r & 15)) << 3];
      }
#pragma unroll
      for (int mf = 0; mf < 8; ++mf) {
        f32x4 a = zz;
#pragma unroll
        for (int k0 = 0; k0 < 2; ++k0) {
          a = __builtin_amdgcn_mfma_f32_16x16x32_bf16(qf[mf][0][k0], kfh[k0], a, 0, 0, 0);
          a = __builtin_amdgcn_mfma_f32_16x16x32_bf16(qf[mf][0][k0], kfl[k0], a, 0, 0, 0);
          a = __builtin_amdgcn_mfma_f32_16x16x32_bf16(qf[mf][1][k0], kfh[k0], a, 0, 0, 0);
        }
#pragma unroll
        for (int j = 0; j < 4; ++j) rmax[mf][j] = fmaxf(rmax[mf][j], a[j]);
      }
    }
    __syncthreads();
  }

  // intra-wave reduce over 16 key lanes; lane fr==0 holds q = mf*16+fk*4+j
#pragma unroll
  for (int mf = 0; mf < 8; ++mf)
#pragma unroll
    for (int j = 0; j < 4; ++j) {
      float r = rmax[mf][j];
      r = fmaxf(r, __shfl_xor(r, 1, 64));
      r = fmaxf(r, __shfl_xor(r, 2, 64));
      r = fmaxf(r, __shfl_xor(r, 4, 64));
      r = fmaxf(r, __shfl_xor(r, 8, 64));
      if (fr == 0) red[w][mf * 16 + fk * 4 + j] = r;
    }
  __syncthreads();

  // cross-wave combine + fused M = (max - q.kbar)/8, one thread per q-row
  if (tid < 128) {
    float mx = fmaxf(fmaxf(red[0][tid], red[1][tid]),
                     fmaxf(red[2][tid], red[3][tid]));
    const short* qp = Qb + (size_t)tid * 128;
    const float* kb = kbarf + bh * 64;
    float dot = 0.f;
#pragma unroll
    for (int ch = 0; ch < 8; ++ch) {
      short8 hi = *(const short8*)(qp + ch * 8);
      short8 lo = *(const short8*)(qp + 64 + ch * 8);
#pragma unroll
      for (int e = 0; e < 8; ++e) dot += (bf2f(hi[e]) + bf2f(lo[e])) * kb[ch * 8 + e];
    }
    Mval[(size_t)bh * 2048 + q0 + tid] = (mx - dot) * 0.125f;
  }
}

// ---------------------------------------------------------------------------
// top-40 per (bh): one WAVE per bh; also writes slot map for the output pass.
// ---------------------------------------------------------------------------
__global__ __launch_bounds__(256) void topk40(const float* __restrict__ Mval,
                                              int* __restrict__ tidx,
                                              int* __restrict__ slot8) {
  __shared__ float vals[4][32][64];
  const int w = threadIdx.x >> 6, lane = threadIdx.x & 63;
  const int bh = blockIdx.x * 4 + w;
  const float* src = Mval + (size_t)bh * 2048;
#pragma unroll
  for (int j = 0; j < 32; ++j) vals[w][j][lane] = src[j * 64 + lane];

  for (int it = 0; it < NU; ++it) {
    float best = -INFINITY;
    int bi = 1 << 30;
#pragma unroll
    for (int j = 0; j < 32; ++j) {
      float x = vals[w][j][lane];
      int idx = j * 64 + lane;
      if (x > best) { best = x; bi = idx; }
    }
#pragma unroll
    for (int off = 1; off < 64; off <<= 1) {
      float ov = __shfl_xor(best, off, 64);
      int oi = __shfl_xor(bi, off, 64);
      if (ov > best || (ov == best && oi < bi)) { best = ov; bi = oi; }
    }
    if (lane == 0) {
      tidx[bh * NU + it] = bi;
      slot8[((size_t)(bh >> 3) * 2048 + bi) * 8 + (bh & 7)] = it;
    }
    if ((bi & 63) == lane) vals[w][bi >> 6][lane] = -INFINITY;
  }
}

// ---------------------------------------------------------------------------
// Dense attention for 40 selected queries, key-split over 4 chunks (partials)
// ---------------------------------------------------------------------------
__global__ __launch_bounds__(256) void topattn1(const short* __restrict__ Qs,
                                                const short* __restrict__ Ks,
                                                const short* __restrict__ Vs,
                                                const int* __restrict__ topidx,
                                                float* __restrict__ pacc,
                                                float* __restrict__ pm,
                                                float* __restrict__ pl) {
  __shared__ float qs[40][68];
  __shared__ float Kst[64][132];
  __shared__ float Vsh[128][68];
  __shared__ float st[40][132];
  __shared__ float m_s[40], l_s[40], r_s[40];
  __shared__ int tix[40];
  const int tid = threadIdx.x;
  const int bh = blockIdx.x, kc = blockIdx.y;
  const short* Kb = Ks + (size_t)bh * 2048 * 128;
  const short* Vb = Vs + (size_t)bh * 2048 * 128;

  if (tid < 40) {
    tix[tid] = topidx[bh * NU + tid];
    m_s[tid] = -INFINITY;
    l_s[tid] = 0.f;
  }
  __syncthreads();
  for (int i = tid; i < 40 * 64; i += 256) {
    int q = i >> 6, dd2 = i & 63;
    const short* qp = Qs + ((size_t)bh * 2048 + tix[q]) * 128;
    qs[q][dd2] = bf2f(qp[dd2]) + bf2f(qp[64 + dd2]);
  }
  const int tx = tid & 31, ty = tid >> 5;
  const int d = tid & 63, qb = tid >> 6;
  float acc[10];
#pragma unroll
  for (int j = 0; j < 10; ++j) acc[j] = 0.f;
  __syncthreads();

  for (int t = 0; t < 4; ++t) {
    int krow0 = kc * 512 + t * 128;
#pragma unroll
    for (int p = 0; p < 4; ++p) {
      int idx = tid + (p << 8);
      int r = idx >> 3, cg = (idx & 7) << 3;
      const short8 kh = *(const short8*)(Kb + (size_t)(krow0 + r) * 128 + cg);
      const short8 kl = *(const short8*)(Kb + (size_t)(krow0 + r) * 128 + 64 + cg);
      const short8 vh = *(const short8*)(Vb + (size_t)(krow0 + r) * 128 + cg);
      const short8 vl = *(const short8*)(Vb + (size_t)(krow0 + r) * 128 + 64 + cg);
#pragma unroll
      for (int j = 0; j < 8; ++j) {
        Kst[cg + j][r] = bf2f(kh[j]) + bf2f(kl[j]);
        Vsh[r][cg + j] = bf2f(vh[j]) + bf2f(vl[j]);
      }
    }
    __syncthreads();

    {
      float c5[5][4];
#pragma unroll
      for (int i = 0; i < 5; ++i)
#pragma unroll
        for (int j = 0; j < 4; ++j) c5[i][j] = 0.f;
      for (int dd = 0; dd < 64; ++dd) {
        const float4 b4 = *(const float4*)&Kst[dd][tx << 2];
#pragma unroll
        for (int i = 0; i < 5; ++i) {
          float a = qs[ty * 5 + i][dd];
          c5[i][0] = fmaf(a, b4.x, c5[i][0]);
          c5[i][1] = fmaf(a, b4.y, c5[i][1]);
          c5[i][2] = fmaf(a, b4.z, c5[i][2]);
          c5[i][3] = fmaf(a, b4.w, c5[i][3]);
        }
      }
#pragma unroll
      for (int i = 0; i < 5; ++i) {
        float4 o;
        o.x = c5[i][0] * 0.125f; o.y = c5[i][1] * 0.125f;
        o.z = c5[i][2] * 0.125f; o.w = c5[i][3] * 0.125f;
        *(float4*)&st[ty * 5 + i][tx << 2] = o;
      }
    }
    __syncthreads();

    if (tid < 160) {
      int q = tid >> 2, sub = tid & 3;
      float tm = -INFINITY;
#pragma unroll
      for (int kk = 0; kk < 32; ++kk) tm = fmaxf(tm, st[q][sub * 32 + kk]);
      tm = fmaxf(tm, __shfl_xor(tm, 1, 64));
      tm = fmaxf(tm, __shfl_xor(tm, 2, 64));
      float mold = m_s[q];
      float mnew = fmaxf(mold, tm);
      float sum = 0.f;
#pragma unroll
      for (int kk = 0; kk < 32; ++kk) {
        float ww = __expf(st[q][sub * 32 + kk] - mnew);
        st[q][sub * 32 + kk] = ww;
        sum += ww;
      }
      sum += __shfl_xor(sum, 1, 64);
      sum += __shfl_xor(sum, 2, 64);
      if (sub == 0) {
        float r = __expf(mold - mnew);
        l_s[q] = l_s[q] * r + sum;
        m_s[q] = mnew;
        r_s[q] = r;
      }
    }
    __syncthreads();

#pragma unroll
    for (int j = 0; j < 10; ++j) {
      int q = qb + (j << 2);
      float a = 0.f;
#pragma unroll
      for (int kk = 0; kk < 128; kk += 4) {
        float4 ww = *(const float4*)&st[q][kk];
        a = fmaf(ww.x, Vsh[kk + 0][d], a);
        a = fmaf(ww.y, Vsh[kk + 1][d], a);
        a = fmaf(ww.z, Vsh[kk + 2][d], a);
        a = fmaf(ww.w, Vsh[kk + 3][d], a);
      }
      acc[j] = acc[j] * r_s[q] + a;
    }
    __syncthreads();
  }

  int pcb = bh * 4 + kc;
#pragma unroll
  for (int j = 0; j < 10; ++j) {
    int q = qb + (j << 2);
    pacc[((size_t)pcb * NU + q) * 64 + d] = acc[j];
  }
  if (tid < 40) {
    pm[pcb * NU + tid] = m_s[tid];
    pl[pcb * NU + tid] = l_s[tid];
  }
}

// ---------------------------------------------------------------------------
// Blocks 0..63: combine partials -> tout; blocks 64..127: om = vbar@Wo+bo
// ---------------------------------------------------------------------------
__global__ __launch_bounds__(256) void topcombine(const float* __restrict__ pacc,
                                                  const float* __restrict__ pm,
                                                  const float* __restrict__ pl,
                                                  float* __restrict__ tout,
                                                  const float* __restrict__ vbarf,
                                                  const float* __restrict__ Wo,
                                                  const float* __restrict__ bo,
                                                  float* __restrict__ om) {
  if (blockIdx.x < 64) {
    const int bh = blockIdx.x;
    const int d = threadIdx.x & 63, qb = threadIdx.x >> 6;
#pragma unroll
    for (int j = 0; j < 10; ++j) {
      int q = qb + (j << 2);
      float m0 = pm[(bh * 4 + 0) * NU + q], m1 = pm[(bh * 4 + 1) * NU + q];
      float m2 = pm[(bh * 4 + 2) * NU + q], m3 = pm[(bh * 4 + 3) * NU + q];
      float mx = fmaxf(fmaxf(m0, m1), fmaxf(m2, m3));
      float e0 = __expf(m0 - mx), e1 = __expf(m1 - mx);
      float e2 = __expf(m2 - mx), e3 = __expf(m3 - mx);
      float L = pl[(bh * 4 + 0) * NU + q] * e0 + pl[(bh * 4 + 1) * NU + q] * e1 +
                pl[(bh * 4 + 2) * NU + q] * e2 + pl[(bh * 4 + 3) * NU + q] * e3;
      float o = (pacc[((size_t)(bh * 4 + 0) * NU + q) * 64 + d] * e0 +
                 pacc[((size_t)(bh * 4 + 1) * NU + q) * 64 + d] * e1 +
                 pacc[((size_t)(bh * 4 + 2) * NU + q) * 64 + d] * e2 +
                 pacc[((size_t)(bh * 4 + 3) * NU + q) * 64 + d] * e3) / L;
      tout[((size_t)bh * NU + q) * 64 + d] = o;
    }
  } else {
    __shared__ float mred[4][64];
    int blk2 = blockIdx.x - 64;          // 0..63
    int b = blk2 >> 3, n0 = (blk2 & 7) * 64;
    int n = n0 + (threadIdx.x & 63), kq = threadIdx.x >> 6;
    const float* vb = vbarf + b * 512;
    float acc = 0.f;
#pragma unroll 8
    for (int k = kq * 128; k < kq * 128 + 128; ++k)
      acc = fmaf(vb[k], Wo[(size_t)k * 512 + n], acc);
    mred[kq][threadIdx.x & 63] = acc;
    __syncthreads();
    if (kq == 0)
      om[b * 512 + n] = bo[n] + mred[0][n - n0] + mred[1][n - n0] +
                        mred[2][n - n0] + mred[3][n - n0];
  }
}

// ---------------------------------------------------------------------------
// Fused output: out[r] = om[b] + sum over selected heads of (tout-vbar)@Wo_h.
// ---------------------------------------------------------------------------
__global__ __launch_bounds__(256) void outall(const float* __restrict__ om,
                                              const int* __restrict__ slot8,
                                              const float* __restrict__ tout,
                                              const float* __restrict__ vbarf,
                                              const float* __restrict__ Wo,
                                              float* __restrict__ out) {
  const int r = blockIdx.x;
  const int b = r >> 11;
  const int n = threadIdx.x;
  float o0 = om[b * 512 + n];
  float o1 = om[b * 512 + n + 256];
  __shared__ float dsh[64];
#pragma unroll
  for (int h = 0; h < 8; ++h) {
    int it = slot8[(size_t)r * 8 + h];
    if (it >= 0) {
      int bh = b * 8 + h;
      int g = bh * NU + it;
      __syncthreads();
      if (n < 64) dsh[n] = tout[(size_t)g * 64 + n] - vbarf[bh * 64 + n];
      __syncthreads();
#pragma unroll 8
      for (int dh = 0; dh < 64; ++dh) {
        float d = dsh[dh];
        const float* wrow = Wo + (size_t)(h * 64 + dh) * 512;
        o0 = fmaf(d, wrow[n], o0);
        o1 = fmaf(d, wrow[n + 256], o1);
      }
    }
  }
  out[(size_t)r * 512 + n] = o0;
  out[(size_t)r * 512 + n + 256] = o1;
}

// ---------------------------------------------------------------------------
extern "C" void kernel_launch(void* const* d_in, const int* in_sizes, int n_in,
                              void* d_out, int out_size, void* d_ws, size_t ws_size,
                              hipStream_t stream) {
  (void)in_sizes; (void)n_in; (void)out_size; (void)ws_size;
  const float* x  = (const float*)d_in[0];
  const float* wq = (const float*)d_in[1];
  const float* bq = (const float*)d_in[2];
  const float* wk = (const float*)d_in[3];
  const float* bk = (const float*)d_in[4];
  const float* wv = (const float*)d_in[5];
  const float* bv = (const float*)d_in[6];
  const float* wo = (const float*)d_in[7];
  const float* bo = (const float*)d_in[8];
  float* out = (float*)d_out;

  short* Wts  = (short*)d_ws;                              // 3*512*1024
  short* Qsb  = Wts + (size_t)3 * 512 * 1024;              // 64*2048*128 each
  short* Ksb  = Qsb + (size_t)NBH * NS * 128;
  short* Vsb  = Ksb + (size_t)NBH * NS * 128;
  float* Mval = (float*)(Vsb + (size_t)NBH * NS * 128);    // 131072
  float* kbarf = Mval + (size_t)NBH * NS;                  // 4096
  float* vbarf = kbarf + NBH * 64;                         // 4096 (contig after kbarf)
  int* tidx   = (int*)(vbarf + NBH * 64);                  // 2560
  int* slot8  = tidx + NBH * NU;                           // 131072
  float* pacc = (float*)(slot8 + (size_t)NM * 8);          // 64*4*40*64
  float* pm   = pacc + (size_t)NBH * 4 * NU * 64;          // 10240
  float* pl   = pm + NBH * 4 * NU;                         // 10240
  float* tout = pl + NBH * 4 * NU;                         // 64*40*64
  float* om   = tout + (size_t)NBH * NU * 64;              // 4096

  prep<<<897, 256, 0, stream>>>(wq, wk, wv, Wts, slot8, kbarf);
  qkvgemm<<<1536, 256, 0, stream>>>(x, Wts, bq, bk, bv, Qsb, Ksb, Vsb, kbarf, vbarf);
  qkmax<<<1024, 256, 0, stream>>>(Qsb, Ksb, kbarf, Mval);
  topk40<<<16, 256, 0, stream>>>(Mval, tidx, slot8);
  topattn1<<<dim3(NBH, 4), 256, 0, stream>>>(Qsb, Ksb, Vsb, tidx, pacc, pm, pl);
  topcombine<<<128, 256, 0, stream>>>(pacc, pm, pl, tout, vbarf, wo, bo, om);
  outall<<<NM, 256, 0, stream>>>(om, slot8, tout, vbarf, wo, out);
}